// Round 5
// baseline (791.525 us; speedup 1.0000x reference)
//
#include <hip/hip_runtime.h>

typedef __attribute__((ext_vector_type(8))) short bf16x8;
typedef __attribute__((ext_vector_type(4))) float f32x4;

#define LDS_STRIDE 136
#define INV_TEMP 0.08838834764831845f   // 1/sqrt(128)

static __device__ __forceinline__ unsigned short f2b(float f) {
    union { float f; unsigned int u; } v; v.f = f;
    unsigned int b = (v.u + 0x7fffu + ((v.u >> 16) & 1u)) >> 16;
    return (unsigned short)b;
}
static __device__ __forceinline__ float b2f(unsigned short s) {
    union { float f; unsigned int u; } v; v.u = ((unsigned int)s) << 16;
    return v.f;
}

// Convert the four 128x128 fp32 weights to bf16 row-major in workspace.
__global__ void prep_weights(const float* __restrict__ Wq, const float* __restrict__ Wk,
                             const float* __restrict__ Wv, const float* __restrict__ Wo,
                             unsigned short* __restrict__ wbf) {
    int i = blockIdx.x * 256 + threadIdx.x;       // 64 blocks x 256 = 16384
    wbf[i]          = f2b(Wq[i]);
    wbf[16384 + i]  = f2b(Wk[i]);
    wbf[32768 + i]  = f2b(Wv[i]);
    wbf[49152 + i]  = f2b(Wo[i]);
}

// 16 waves (1024 threads), 1 block/CU (LDS 142 KB), 4 waves/SIMD resident.
// Hard constraint: 4 waves/SIMD => <=128 unified VGPR+AGPR per wave. The
// flash-loop build phase is register-peak; it is split into K-pass / V-pass
// so only one weight-frag set (16 VGPRs) is live at a time (~107 peak).
__launch_bounds__(1024, 4)
__global__ void patch_attn(const float* __restrict__ x,
                           const float* __restrict__ bq, const float* __restrict__ bk,
                           const float* __restrict__ bv, const float* __restrict__ bo,
                           const unsigned short* __restrict__ wbf,
                           float* __restrict__ out)
{
    __shared__ __align__(16) unsigned short sPT[256 * LDS_STRIDE];  // 69,632 B, persistent
    __shared__ __align__(16) unsigned char  sUN[72704];             // time-multiplexed union

    const int tid  = threadIdx.x;
    const int w    = tid >> 6;         // 0..15
    const int lane = tid & 63;
    const int quad = lane >> 4;
    const int l16  = lane & 15;
    const int half = w & 1;            // token-half in projection phases
    const int dcol = (w >> 1) * 16 + l16;  // this wave's output column in build phases
    const int lbase = w * 16;          // this wave's 16 tokens in the flash loop

    const int pid = blockIdx.x;            // 2048 patches
    const int b   = pid >> 10;
    const int n   = pid & 1023;
    const int gy  = n >> 5, gx = n & 31;
    const long patch_off = ((long)(b * 128) * 512 + gy * 16) * 512 + gx * 16;

    const unsigned short* Wq_bf = wbf;
    const unsigned short* Wk_bf = wbf + 16384;
    const unsigned short* Wv_bf = wbf + 32768;
    const unsigned short* Wo_bf = wbf + 49152;

    // ---------------- Phase 0: stage patch token-major (bf16) ----------------
    // Lane-quad holds 4 channels x 4 tokens; 4x4 shfl transpose -> one aligned
    // b64 write of 4 consecutive channels per lane.
    {
        const int dc = lane & 3, g = lane >> 2;
        const int l0 = ((w & 3) * 16 + g) * 4;        // 4-token group, same for quad
        const int sh = l0 >> 4, sw = l0 & 15;
        const int cbh = w >> 2;                       // 0..3
        for (int it = 0; it < 8; ++it) {
            const int c0 = (it * 4 + cbh) * 4;        // channel block of 4
            const float4 f = *(const float4*)(x + patch_off + ((long)(c0 + dc) * 512 + sh) * 512 + sw);
            unsigned int A = (unsigned int)f2b(f.x) | ((unsigned int)f2b(f.y) << 16);
            unsigned int B = (unsigned int)f2b(f.z) | ((unsigned int)f2b(f.w) << 16);
            // 4x4 short transpose across the quad (masks 1 then 2)
            unsigned int Pa = __shfl_xor(A, 1);
            unsigned int Pb = __shfl_xor(B, 1);
            unsigned int A1 = (dc & 1) ? ((Pa >> 16) | (A & 0xffff0000u))
                                       : ((A & 0x0000ffffu) | (Pa << 16));
            unsigned int B1 = (dc & 1) ? ((Pb >> 16) | (B & 0xffff0000u))
                                       : ((B & 0x0000ffffu) | (Pb << 16));
            unsigned int Ra = __shfl_xor(A1, 2);
            unsigned int Rb = __shfl_xor(B1, 2);
            uint2 o;
            o.x = (dc & 2) ? Rb : A1;   // channels c0+0,c0+1 at token l0+dc
            o.y = (dc & 2) ? B1 : Ra;   // channels c0+2,c0+3 at token l0+dc
            *(uint2*)&sPT[(l0 + dc) * LDS_STRIDE + c0] = o;
        }
    }
    __syncthreads();

    // ---------------- Phase 1: q-projection --------------------------------
    // Wave w: d-tile w>>1, tokens half (w&1). Weight frags in 16 VGPRs.
    unsigned short* qscr = (unsigned short*)sUN;     // [256][136]
    {
        bf16x8 wq[4];
#pragma unroll
        for (int ks = 0; ks < 4; ++ks)
            wq[ks] = *(const bf16x8*)(Wq_bf + dcol * 128 + ks * 32 + quad * 8);
        const float qb = bq[dcol];
#pragma unroll
        for (int lt8 = 0; lt8 < 8; ++lt8) {
            const int lt = half * 8 + lt8;
            f32x4 acc = {0.f, 0.f, 0.f, 0.f};
#pragma unroll
            for (int ks = 0; ks < 4; ++ks) {
                bf16x8 a = *(const bf16x8*)&sPT[(lt * 16 + l16) * LDS_STRIDE + ks * 32 + quad * 8];
                acc = __builtin_amdgcn_mfma_f32_16x16x32_bf16(a, wq[ks], acc, 0, 0, 0);
            }
#pragma unroll
            for (int r = 0; r < 4; ++r)
                qscr[(lt * 16 + quad * 4 + r) * LDS_STRIDE + dcol] = f2b((acc[r] + qb) * INV_TEMP);
        }
    }
    __syncthreads();
    // read back own 16 rows as A-fragments
    bf16x8 qfrag[4];
#pragma unroll
    for (int ks = 0; ks < 4; ++ks)
        qfrag[ks] = *(const bf16x8*)&qscr[(lbase + l16) * LDS_STRIDE + ks * 32 + quad * 8];
    __syncthreads();   // release union region for the flash loop

    // ---------------- Phase 2: flash over 4 key-chunks of 64 -----------------
    unsigned short* kTc = (unsigned short*)sUN;                       // [64][136]
    unsigned short* vTc = (unsigned short*)(sUN + 17408);             // [128][72]
    unsigned short* Pw  = (unsigned short*)(sUN + 35840) + w * (16 * 72); // per-wave [16][72]

    const float kb = bk[dcol], vb = bv[dcol];

    f32x4 O[8];
#pragma unroll
    for (int dt = 0; dt < 8; ++dt) O[dt] = (f32x4){0.f, 0.f, 0.f, 0.f};
    float mrow[4], lrow[4];
#pragma unroll
    for (int r = 0; r < 4; ++r) { mrow[r] = -1e30f; lrow[r] = 0.f; }

    for (int ch = 0; ch < 4; ++ch) {
        const int m0 = ch * 64;
        // ---- K pass: only wk (16 VGPRs) + kacc (4) live -------------------
        {
            const unsigned short* wp = Wk_bf;
            asm volatile("" : "+s"(wp));   // block LICM/CSE: keep live range per-pass
            bf16x8 wk[4];
#pragma unroll
            for (int ks = 0; ks < 4; ++ks)
                wk[ks] = *(const bf16x8*)(wp + dcol * 128 + ks * 32 + quad * 8);
#pragma unroll
            for (int mt2 = 0; mt2 < 2; ++mt2) {
                const int mt = half * 2 + mt2;
                f32x4 kacc = {0.f, 0.f, 0.f, 0.f};
#pragma unroll
                for (int ks = 0; ks < 4; ++ks) {
                    bf16x8 a = *(const bf16x8*)&sPT[(m0 + mt * 16 + l16) * LDS_STRIDE + ks * 32 + quad * 8];
                    kacc = __builtin_amdgcn_mfma_f32_16x16x32_bf16(a, wk[ks], kacc, 0, 0, 0);
                }
#pragma unroll
                for (int r = 0; r < 4; ++r)
                    kTc[(mt * 16 + quad * 4 + r) * LDS_STRIDE + dcol] = f2b(kacc[r] + kb);
            }
        }
        // ---- V pass: only wv (16 VGPRs) + vacc (4) live -------------------
        {
            const unsigned short* wp = Wv_bf;
            asm volatile("" : "+s"(wp));
            bf16x8 wv[4];
#pragma unroll
            for (int ks = 0; ks < 4; ++ks)
                wv[ks] = *(const bf16x8*)(wp + dcol * 128 + ks * 32 + quad * 8);
#pragma unroll
            for (int mt2 = 0; mt2 < 2; ++mt2) {
                const int mt = half * 2 + mt2;
                f32x4 vacc = {0.f, 0.f, 0.f, 0.f};
#pragma unroll
                for (int ks = 0; ks < 4; ++ks) {
                    bf16x8 a = *(const bf16x8*)&sPT[(m0 + mt * 16 + l16) * LDS_STRIDE + ks * 32 + quad * 8];
                    vacc = __builtin_amdgcn_mfma_f32_16x16x32_bf16(a, wv[ks], vacc, 0, 0, 0);
                }
                unsigned short vp[4];
#pragma unroll
                for (int r = 0; r < 4; ++r) vp[r] = f2b(vacc[r] + vb);
                unsigned long long pk = (unsigned long long)vp[0]
                                      | ((unsigned long long)vp[1] << 16)
                                      | ((unsigned long long)vp[2] << 32)
                                      | ((unsigned long long)vp[3] << 48);
                *(unsigned long long*)&vTc[dcol * 72 + mt * 16 + quad * 4] = pk;
            }
        }
        __syncthreads();

        // S = q . kT^T, online softmax (defer-max), P -> LDS, O += P . v
        {
            f32x4 s[4];
#pragma unroll
            for (int nt = 0; nt < 4; ++nt) {
                f32x4 acc = {0.f, 0.f, 0.f, 0.f};
#pragma unroll
                for (int ks = 0; ks < 4; ++ks) {
                    bf16x8 bb = *(const bf16x8*)&kTc[(nt * 16 + l16) * LDS_STRIDE + ks * 32 + quad * 8];
                    acc = __builtin_amdgcn_mfma_f32_16x16x32_bf16(qfrag[ks], bb, acc, 0, 0, 0);
                }
                s[nt] = acc;
            }
            float mx[4];
#pragma unroll
            for (int r = 0; r < 4; ++r) {
                float m = fmaxf(fmaxf(s[0][r], s[1][r]), fmaxf(s[2][r], s[3][r]));
#pragma unroll
                for (int off = 8; off; off >>= 1) m = fmaxf(m, __shfl_xor(m, off));
                mx[r] = m;
            }
            // T13 defer-max: skip the O-wide rescale while growth <= 8 (exact math,
            // P bounded by e^8). First chunk always takes the rescale path.
            bool need = false;
#pragma unroll
            for (int r = 0; r < 4; ++r) need |= (mx[r] - mrow[r] > 8.f);
            if (__any(need)) {
#pragma unroll
                for (int r = 0; r < 4; ++r) {
                    float mnew  = fmaxf(mrow[r], mx[r]);
                    float alpha = __expf(mrow[r] - mnew);
                    mrow[r] = mnew;
                    lrow[r] *= alpha;
#pragma unroll
                    for (int dt = 0; dt < 8; ++dt) O[dt][r] *= alpha;
                }
            }
#pragma unroll
            for (int r = 0; r < 4; ++r) {
                float rs = 0.f;
#pragma unroll
                for (int nt = 0; nt < 4; ++nt) {
                    float p = __expf(s[nt][r] - mrow[r]);
                    s[nt][r] = p;
                    rs += p;
                }
#pragma unroll
                for (int off = 8; off; off >>= 1) rs += __shfl_xor(rs, off);
                lrow[r] += rs;
            }
#pragma unroll
            for (int nt = 0; nt < 4; ++nt)
#pragma unroll
                for (int r = 0; r < 4; ++r)
                    Pw[(quad * 4 + r) * 72 + nt * 16 + l16] = f2b(s[nt][r]);
#pragma unroll
            for (int dt = 0; dt < 8; ++dt) {
                f32x4 acc = O[dt];
#pragma unroll
                for (int kt = 0; kt < 2; ++kt) {
                    bf16x8 pa = *(const bf16x8*)&Pw[l16 * 72 + kt * 32 + quad * 8];
                    bf16x8 vv = *(const bf16x8*)&vTc[(dt * 16 + l16) * 72 + kt * 32 + quad * 8];
                    acc = __builtin_amdgcn_mfma_f32_16x16x32_bf16(pa, vv, acc, 0, 0, 0);
                }
                O[dt] = acc;
            }
        }
        __syncthreads();   // protect kTc/vTc overwrite next chunk (and yA reuse after)
    }

    // ---------------- Phase 3: normalize, O-projection, residual, store ------
    unsigned short* yA = (unsigned short*)sUN;   // [256][136] (flash region is dead)
    {
        float inv[4];
#pragma unroll
        for (int r = 0; r < 4; ++r) inv[r] = 1.f / lrow[r];
#pragma unroll
        for (int dt = 0; dt < 8; ++dt)
#pragma unroll
            for (int r = 0; r < 4; ++r)
                yA[(lbase + quad * 4 + r) * LDS_STRIDE + dt * 16 + l16] =
                    f2b(O[dt][r] * inv[r]);
    }
    __syncthreads();   // wave w now reads other waves' rows of yA

    {
        bf16x8 wo[4];
#pragma unroll
        for (int ks = 0; ks < 4; ++ks)
            wo[ks] = *(const bf16x8*)(Wo_bf + dcol * 128 + ks * 32 + quad * 8);
        const float ob = bo[dcol];
        float* outc = out + patch_off + (long)dcol * 262144;
#pragma unroll
        for (int lt8 = 0; lt8 < 8; ++lt8) {
            const int lt = half * 8 + lt8;
            f32x4 acc = {0.f, 0.f, 0.f, 0.f};
#pragma unroll
            for (int ks = 0; ks < 4; ++ks) {
                bf16x8 a = *(const bf16x8*)&yA[(lt * 16 + l16) * LDS_STRIDE + ks * 32 + quad * 8];
                acc = __builtin_amdgcn_mfma_f32_16x16x32_bf16(a, wo[ks], acc, 0, 0, 0);
            }
            f32x4 o4;
#pragma unroll
            for (int r = 0; r < 4; ++r)
                o4[r] = acc[r] + ob + b2f(sPT[(lt * 16 + quad * 4 + r) * LDS_STRIDE + dcol]);
            *(f32x4*)(outc + lt * 512 + quad * 4) = o4;   // rows quad*4+r are consecutive sw
        }
    }
}

extern "C" void kernel_launch(void* const* d_in, const int* in_sizes, int n_in,
                              void* d_out, int out_size, void* d_ws, size_t ws_size,
                              hipStream_t stream) {
    (void)in_sizes; (void)n_in; (void)out_size; (void)ws_size;
    const float* x  = (const float*)d_in[0];
    const float* Wq = (const float*)d_in[1];
    const float* bq = (const float*)d_in[2];
    const float* Wk = (const float*)d_in[3];
    const float* bk = (const float*)d_in[4];
    const float* Wv = (const float*)d_in[5];
    const float* bv = (const float*)d_in[6];
    const float* Wo = (const float*)d_in[7];
    const float* bo = (const float*)d_in[8];
    unsigned short* wbf = (unsigned short*)d_ws;   // 131,072 B of bf16 weights

    prep_weights<<<64, 256, 0, stream>>>(Wq, Wk, Wv, Wo, wbf);
    patch_attn<<<2048, 1024, 0, stream>>>(x, bq, bk, bv, bo, wbf, (float*)d_out);
}

// Round 9
// 694.552 us; speedup vs baseline: 1.1396x; 1.1396x over previous
//
#include <hip/hip_runtime.h>

typedef __attribute__((ext_vector_type(8))) short bf16x8;
typedef __attribute__((ext_vector_type(4))) float f32x4;

#define LDS_STRIDE 136
#define INV_TEMP 0.08838834764831845f   // 1/sqrt(128)

static __device__ __forceinline__ unsigned short f2b(float f) {
    union { float f; unsigned int u; } v; v.f = f;
    unsigned int b = (v.u + 0x7fffu + ((v.u >> 16) & 1u)) >> 16;
    return (unsigned short)b;
}
static __device__ __forceinline__ float b2f(unsigned short s) {
    union { float f; unsigned int u; } v; v.u = ((unsigned int)s) << 16;
    return v.f;
}

// Convert the four 128x128 fp32 weights to bf16 row-major in workspace.
__global__ void prep_weights(const float* __restrict__ Wq, const float* __restrict__ Wk,
                             const float* __restrict__ Wv, const float* __restrict__ Wo,
                             unsigned short* __restrict__ wbf) {
    int i = blockIdx.x * 256 + threadIdx.x;       // 64 blocks x 256 = 16384
    wbf[i]          = f2b(Wq[i]);
    wbf[16384 + i]  = f2b(Wk[i]);
    wbf[32768 + i]  = f2b(Wv[i]);
    wbf[49152 + i]  = f2b(Wo[i]);
}

// 8 waves (512 threads), 1 block/CU (LDS 142 KB), 2 waves/SIMD. Register
// budget 256/wave -> no spill (R1 measured VGPR=108, clean HBM traffic).
// Latency attacked via register-pipelined K/V build: chunk ch+1's K/V tiles
// are computed into registers while chunk ch's attention runs (independent
// instruction streams within the wave).
__launch_bounds__(512, 2)
__global__ void patch_attn(const float* __restrict__ x,
                           const float* __restrict__ bq, const float* __restrict__ bk,
                           const float* __restrict__ bv, const float* __restrict__ bo,
                           const unsigned short* __restrict__ wbf,
                           float* __restrict__ out)
{
    __shared__ __align__(16) unsigned short sPT[256 * LDS_STRIDE];  // 69,632 B, persistent
    __shared__ __align__(16) unsigned char  sUN[72704];             // time-multiplexed union

    const int tid  = threadIdx.x;
    const int w    = tid >> 6;         // 0..7
    const int lane = tid & 63;
    const int quad = lane >> 4;
    const int l16  = lane & 15;
    const int dcol = w * 16 + l16;     // this wave's output column in build phases
    const int lbase = w * 32;          // this wave's 32 tokens in the flash loop

    const int pid = blockIdx.x;            // 2048 patches
    const int b   = pid >> 10;
    const int n   = pid & 1023;
    const int gy  = n >> 5, gx = n & 31;
    const long patch_off = ((long)(b * 128) * 512 + gy * 16) * 512 + gx * 16;

    const unsigned short* Wq_bf = wbf;
    const unsigned short* Wk_bf = wbf + 16384;
    const unsigned short* Wv_bf = wbf + 32768;
    const unsigned short* Wo_bf = wbf + 49152;

    // ---------------- Phase 0: stage patch token-major (bf16) ----------------
    // Lane-quad holds 4 channels x 4 tokens; 4x4 shfl transpose -> one aligned
    // b64 write of 4 consecutive channels per lane.
    {
        const int dc = lane & 3, g = lane >> 2;
        const int l0 = ((w & 3) * 16 + g) * 4;        // 4-token group, same for quad
        const int sh = l0 >> 4, sw = l0 & 15;
        const int cbh = tid >> 8;                     // 0 or 1
        for (int it = 0; it < 16; ++it) {
            const int c0 = (it * 2 + cbh) * 4;        // channel block of 4
            const float4 f = *(const float4*)(x + patch_off + ((long)(c0 + dc) * 512 + sh) * 512 + sw);
            unsigned int A = (unsigned int)f2b(f.x) | ((unsigned int)f2b(f.y) << 16);
            unsigned int B = (unsigned int)f2b(f.z) | ((unsigned int)f2b(f.w) << 16);
            unsigned int Pa = __shfl_xor(A, 1);
            unsigned int Pb = __shfl_xor(B, 1);
            unsigned int A1 = (dc & 1) ? ((Pa >> 16) | (A & 0xffff0000u))
                                       : ((A & 0x0000ffffu) | (Pa << 16));
            unsigned int B1 = (dc & 1) ? ((Pb >> 16) | (B & 0xffff0000u))
                                       : ((B & 0x0000ffffu) | (Pb << 16));
            unsigned int Ra = __shfl_xor(A1, 2);
            unsigned int Rb = __shfl_xor(B1, 2);
            uint2 o;
            o.x = (dc & 2) ? Rb : A1;   // channels c0+0,c0+1 at token l0+dc
            o.y = (dc & 2) ? B1 : Ra;   // channels c0+2,c0+3 at token l0+dc
            *(uint2*)&sPT[(l0 + dc) * LDS_STRIDE + c0] = o;
        }
    }
    __syncthreads();

    // Hoisted K/V weight frags + biases (live across the whole kernel; 512t
    // has 256-reg budget so this is free).
    bf16x8 wk[4], wv[4];
#pragma unroll
    for (int ks = 0; ks < 4; ++ks) {
        wk[ks] = *(const bf16x8*)(Wk_bf + dcol * 128 + ks * 32 + quad * 8);
        wv[ks] = *(const bf16x8*)(Wv_bf + dcol * 128 + ks * 32 + quad * 8);
    }
    const float kb = bk[dcol], vb = bv[dcol];

    // Register-staged next-chunk K/V (packed bf16, bias applied)
    unsigned int kp01[4], kp23[4];
    unsigned long long vpk[4];

#define BUILD_KV(M0)                                                              \
    {                                                                             \
        _Pragma("unroll")                                                         \
        for (int mt = 0; mt < 4; ++mt) {                                          \
            f32x4 kacc = {0.f, 0.f, 0.f, 0.f}, vacc = {0.f, 0.f, 0.f, 0.f};       \
            _Pragma("unroll")                                                     \
            for (int ks = 0; ks < 4; ++ks) {                                      \
                bf16x8 a = *(const bf16x8*)&sPT[((M0) + mt * 16 + l16) * LDS_STRIDE + ks * 32 + quad * 8]; \
                kacc = __builtin_amdgcn_mfma_f32_16x16x32_bf16(a, wk[ks], kacc, 0, 0, 0); \
                vacc = __builtin_amdgcn_mfma_f32_16x16x32_bf16(a, wv[ks], vacc, 0, 0, 0); \
            }                                                                     \
            kp01[mt] = (unsigned int)f2b(kacc[0] + kb) | ((unsigned int)f2b(kacc[1] + kb) << 16); \
            kp23[mt] = (unsigned int)f2b(kacc[2] + kb) | ((unsigned int)f2b(kacc[3] + kb) << 16); \
            vpk[mt]  = (unsigned long long)f2b(vacc[0] + vb)                      \
                     | ((unsigned long long)f2b(vacc[1] + vb) << 16)              \
                     | ((unsigned long long)f2b(vacc[2] + vb) << 32)              \
                     | ((unsigned long long)f2b(vacc[3] + vb) << 48);             \
        }                                                                         \
    }

    // ---------------- Phase 1: q-projection (wave w owns d-tile w) -----------
    unsigned short* qscr = (unsigned short*)sUN;     // [256][136]
    {
        bf16x8 wq[4];
#pragma unroll
        for (int ks = 0; ks < 4; ++ks)
            wq[ks] = *(const bf16x8*)(Wq_bf + dcol * 128 + ks * 32 + quad * 8);
        const float qb = bq[dcol];
#pragma unroll
        for (int lt = 0; lt < 16; ++lt) {
            f32x4 acc = {0.f, 0.f, 0.f, 0.f};
#pragma unroll
            for (int ks = 0; ks < 4; ++ks) {
                bf16x8 a = *(const bf16x8*)&sPT[(lt * 16 + l16) * LDS_STRIDE + ks * 32 + quad * 8];
                acc = __builtin_amdgcn_mfma_f32_16x16x32_bf16(a, wq[ks], acc, 0, 0, 0);
            }
#pragma unroll
            for (int r = 0; r < 4; ++r)
                qscr[(lt * 16 + quad * 4 + r) * LDS_STRIDE + dcol] = f2b((acc[r] + qb) * INV_TEMP);
        }
    }
    // Build chunk 0's K/V into registers — independent of qscr, overlaps above.
    BUILD_KV(0);
    __syncthreads();
    // read back own 32 rows as A-fragments
    bf16x8 qfrag[2][4];
#pragma unroll
    for (int lt = 0; lt < 2; ++lt)
#pragma unroll
        for (int ks = 0; ks < 4; ++ks)
            qfrag[lt][ks] = *(const bf16x8*)&qscr[(lbase + lt * 16 + l16) * LDS_STRIDE + ks * 32 + quad * 8];
    __syncthreads();   // release union region for the flash loop

    // ---------------- Phase 2: flash over 4 key-chunks of 64 -----------------
    unsigned short* kTc = (unsigned short*)sUN;                       // [64][136]
    unsigned short* vTc = (unsigned short*)(sUN + 17408);             // [128][72]
    unsigned short* Pw  = (unsigned short*)(sUN + 35840) + w * (32 * 72); // per-wave [32][72]

    f32x4 O[2][8];
#pragma unroll
    for (int lt = 0; lt < 2; ++lt)
#pragma unroll
        for (int dt = 0; dt < 8; ++dt) O[lt][dt] = (f32x4){0.f, 0.f, 0.f, 0.f};
    float mrow[2][4], lrow[2][4];
#pragma unroll
    for (int lt = 0; lt < 2; ++lt)
#pragma unroll
        for (int r = 0; r < 4; ++r) { mrow[lt][r] = -1e30f; lrow[lt][r] = 0.f; }

#pragma unroll
    for (int ch = 0; ch < 4; ++ch) {
        // ---- store pre-built K/V registers -> LDS (short critical section) --
#pragma unroll
        for (int mt = 0; mt < 4; ++mt) {
            const int row = mt * 16 + quad * 4;
            kTc[(row + 0) * LDS_STRIDE + dcol] = (unsigned short)(kp01[mt]);
            kTc[(row + 1) * LDS_STRIDE + dcol] = (unsigned short)(kp01[mt] >> 16);
            kTc[(row + 2) * LDS_STRIDE + dcol] = (unsigned short)(kp23[mt]);
            kTc[(row + 3) * LDS_STRIDE + dcol] = (unsigned short)(kp23[mt] >> 16);
            *(unsigned long long*)&vTc[dcol * 72 + mt * 16 + quad * 4] = vpk[mt];
        }
        __syncthreads();

        // ---- build NEXT chunk's K/V into registers; overlaps attention ------
        if (ch < 3) BUILD_KV((ch + 1) * 64);

        // ---- S = q . kT^T, online softmax (defer-max), P -> LDS, O += P . v -
#pragma unroll
        for (int lt = 0; lt < 2; ++lt) {
            f32x4 s[4];
#pragma unroll
            for (int nt = 0; nt < 4; ++nt) {
                f32x4 acc = {0.f, 0.f, 0.f, 0.f};
#pragma unroll
                for (int ks = 0; ks < 4; ++ks) {
                    bf16x8 bb = *(const bf16x8*)&kTc[(nt * 16 + l16) * LDS_STRIDE + ks * 32 + quad * 8];
                    acc = __builtin_amdgcn_mfma_f32_16x16x32_bf16(qfrag[lt][ks], bb, acc, 0, 0, 0);
                }
                s[nt] = acc;
            }
            float mx[4];
#pragma unroll
            for (int r = 0; r < 4; ++r) {
                float m = fmaxf(fmaxf(s[0][r], s[1][r]), fmaxf(s[2][r], s[3][r]));
#pragma unroll
                for (int off = 8; off; off >>= 1) m = fmaxf(m, __shfl_xor(m, off));
                mx[r] = m;
            }
            // T13 defer-max: skip O-wide rescale while growth <= 8 (P <= e^8).
            bool need = false;
#pragma unroll
            for (int r = 0; r < 4; ++r) need |= (mx[r] - mrow[lt][r] > 8.f);
            if (__any(need)) {
#pragma unroll
                for (int r = 0; r < 4; ++r) {
                    float mnew  = fmaxf(mrow[lt][r], mx[r]);
                    float alpha = __expf(mrow[lt][r] - mnew);
                    mrow[lt][r] = mnew;
                    lrow[lt][r] *= alpha;
#pragma unroll
                    for (int dt = 0; dt < 8; ++dt) O[lt][dt][r] *= alpha;
                }
            }
#pragma unroll
            for (int r = 0; r < 4; ++r) {
                float rs = 0.f;
#pragma unroll
                for (int nt = 0; nt < 4; ++nt) {
                    float p = __expf(s[nt][r] - mrow[lt][r]);
                    s[nt][r] = p;
                    rs += p;
                }
#pragma unroll
                for (int off = 8; off; off >>= 1) rs += __shfl_xor(rs, off);
                lrow[lt][r] += rs;
            }
#pragma unroll
            for (int nt = 0; nt < 4; ++nt)
#pragma unroll
                for (int r = 0; r < 4; ++r)
                    Pw[(lt * 16 + quad * 4 + r) * 72 + nt * 16 + l16] = f2b(s[nt][r]);
#pragma unroll
            for (int dt = 0; dt < 8; ++dt) {
                f32x4 acc = O[lt][dt];
#pragma unroll
                for (int kt = 0; kt < 2; ++kt) {
                    bf16x8 pa = *(const bf16x8*)&Pw[(lt * 16 + l16) * 72 + kt * 32 + quad * 8];
                    bf16x8 vv = *(const bf16x8*)&vTc[(dt * 16 + l16) * 72 + kt * 32 + quad * 8];
                    acc = __builtin_amdgcn_mfma_f32_16x16x32_bf16(pa, vv, acc, 0, 0, 0);
                }
                O[lt][dt] = acc;
            }
        }
        __syncthreads();   // protect kTc/vTc overwrite next chunk (and yA reuse after)
    }
#undef BUILD_KV

    // ---------------- Phase 3: normalize, O-projection, residual, store ------
    unsigned short* yA = (unsigned short*)sUN;   // [256][136] (flash region is dead)
#pragma unroll
    for (int lt = 0; lt < 2; ++lt) {
        float inv[4];
#pragma unroll
        for (int r = 0; r < 4; ++r) inv[r] = 1.f / lrow[lt][r];
#pragma unroll
        for (int dt = 0; dt < 8; ++dt)
#pragma unroll
            for (int r = 0; r < 4; ++r)
                yA[(lbase + lt * 16 + quad * 4 + r) * LDS_STRIDE + dt * 16 + l16] =
                    f2b(O[lt][dt][r] * inv[r]);
    }
    __syncthreads();   // wave w now reads all rows of yA for its dcol

    {
        bf16x8 wo[4];
#pragma unroll
        for (int ks = 0; ks < 4; ++ks)
            wo[ks] = *(const bf16x8*)(Wo_bf + dcol * 128 + ks * 32 + quad * 8);
        const float ob = bo[dcol];
        float* outc = out + patch_off + (long)dcol * 262144;
#pragma unroll
        for (int lt = 0; lt < 16; ++lt) {
            f32x4 acc = {0.f, 0.f, 0.f, 0.f};
#pragma unroll
            for (int ks = 0; ks < 4; ++ks) {
                bf16x8 a = *(const bf16x8*)&yA[(lt * 16 + l16) * LDS_STRIDE + ks * 32 + quad * 8];
                acc = __builtin_amdgcn_mfma_f32_16x16x32_bf16(a, wo[ks], acc, 0, 0, 0);
            }
            f32x4 o4;
#pragma unroll
            for (int r = 0; r < 4; ++r)
                o4[r] = acc[r] + ob + b2f(sPT[(lt * 16 + quad * 4 + r) * LDS_STRIDE + dcol]);
            *(f32x4*)(outc + lt * 512 + quad * 4) = o4;   // rows quad*4+r are consecutive sw
        }
    }
}

extern "C" void kernel_launch(void* const* d_in, const int* in_sizes, int n_in,
                              void* d_out, int out_size, void* d_ws, size_t ws_size,
                              hipStream_t stream) {
    (void)in_sizes; (void)n_in; (void)out_size; (void)ws_size;
    const float* x  = (const float*)d_in[0];
    const float* Wq = (const float*)d_in[1];
    const float* bq = (const float*)d_in[2];
    const float* Wk = (const float*)d_in[3];
    const float* bk = (const float*)d_in[4];
    const float* Wv = (const float*)d_in[5];
    const float* bv = (const float*)d_in[6];
    const float* Wo = (const float*)d_in[7];
    const float* bo = (const float*)d_in[8];
    unsigned short* wbf = (unsigned short*)d_ws;   // 131,072 B of bf16 weights

    prep_weights<<<64, 256, 0, stream>>>(Wq, Wk, Wv, Wo, wbf);
    patch_attn<<<2048, 512, 0, stream>>>(x, bq, bk, bv, bo, wbf, (float*)d_out);
}